// Round 3
// baseline (264.282 us; speedup 1.0000x reference)
//
#include <hip/hip_runtime.h>

#define B_ 8
#define N_ 4096
#define C_ 512

typedef _Float16 f16;
typedef __attribute__((ext_vector_type(8))) _Float16 f16x8;
typedef __attribute__((ext_vector_type(4))) _Float16 f16x4;
typedef __attribute__((ext_vector_type(4))) float f32x4;

#define TILE_E (128 * 32)

// global -> LDS async copy, 16B per lane. LDS dest must be wave-uniform base;
// lane adds l*16 in hardware. Global src is per-lane.
#define GLL16(gsrc, ldst)                                                      \
  __builtin_amdgcn_global_load_lds(                                            \
      (const __attribute__((address_space(1))) void*)(gsrc),                   \
      (__attribute__((address_space(3))) void*)(ldst), 16, 0, 0)

__device__ __forceinline__ int xcd_remap(int bid, int nwg) {
  // nwg % 8 == 0 for all our grids -> bijective chunked remap (T1)
  return (bid & 7) * (nwg >> 3) + (bid >> 3);
}

#define SBAR() asm volatile("s_barrier" ::: "memory")
#define SFENCE() __builtin_amdgcn_sched_barrier(0)

// ---------------------------------------------------------------------------
// 8-phase 256x256 mainloop (BK=64, 8 waves 2Mx4N, per-wave 128x64 output),
// generalized to NTT total K-steps processed as G = NTT/SUBNT sub-problems
// (persistent multi-tile: the pipeline never drains at sub-tile boundaries;
// epi(g,acc) is invoked after each sub-tile's last phase, then acc re-zeroed).
// asrc(t)/bsrc(t) return the byte base of the [256][64] K-block t (h=0 row 0).
// LDS: 4 half-slots/matrix of [128][64] f16, st_16x32 swizzled. Residency
// invariant (unchanged from verified 4-phase schedule): vmcnt(6) at ph4
// leaves exactly stages {T+2:A0,A1,B0} outstanding -> tile T+1 resident.
// Requires SUBNT even so LDS parity (T&1) == (Ti&1).
// ---------------------------------------------------------------------------
template <int LDA2, int LDB2, int NTT, int SUBNT, typename ASrc, typename BSrc,
          typename Epi>
__device__ __forceinline__ void mainloop8p(ASrc asrc, BSrc bsrc, f16* Als,
                                           f16* Bls, Epi epi) {
  const int tid = threadIdx.x;
  const int lane = tid & 63;
  const int wv = tid >> 6;
  const int wr = wv >> 2;   // M half (0..1)
  const int wcq = wv & 3;   // N quarter (0..3)

  // fragment LDS offsets (f16 elements), swizzle folded to lane-constant XOR
  const int kpart = ((lane >> 4) * 8) ^ ((lane & 4) << 2);
  const int abase = (lane & 15) * 64 + kpart;
  const int bbase = ((wcq & 1) * 64 + (lane & 15)) * 64 + kpart;

  // stage per-lane source offsets (bytes within a [128][64-elem] half tile)
  int rowl[2], colb[2];
#pragma unroll
  for (int ld = 0; ld < 2; ++ld) {
    const int doff = (ld * 512 + tid) * 16;
    const int off2 = doff ^ (((doff >> 9) & 1) << 5);
    rowl[ld] = off2 >> 7;
    colb[ld] = off2 & 127;
  }

  f32x4 acc[8][4];
#pragma unroll
  for (int zi = 0; zi < 8; ++zi)
#pragma unroll
    for (int zj = 0; zj < 4; ++zj) {
      f32x4 z = {0.f, 0.f, 0.f, 0.f};
      acc[zi][zj] = z;
    }

  auto stage = [&](int t, int mat, int h) {
    if (t >= NTT) return;
    const char* s0 = mat ? bsrc(t) : asrc(t);
    const int LD2 = mat ? LDB2 : LDA2;
    f16* lsl = (mat ? Bls : Als) + ((t & 1) * 2 + h) * 8192 + wv * 512;
#pragma unroll
    for (int ld = 0; ld < 2; ++ld)
      GLL16(s0 + (size_t)(h * 128 + rowl[ld]) * LD2 + colb[ld],
            lsl + ld * 4096);
  };

  // prologue: tile0 {A0,A1,B0,B1}, tile1 {A0,A1,B0} -> 14 loads in flight
  stage(0, 0, 0); stage(0, 0, 1); stage(0, 1, 0); stage(0, 1, 1);
  stage(1, 0, 0); stage(1, 0, 1); stage(1, 1, 0);
  asm volatile("s_waitcnt vmcnt(6)" ::: "memory");  // tile0 resident
  SBAR();
  SFENCE();

#pragma unroll 1
  for (int g = 0; g < NTT / SUBNT; ++g) {
#pragma unroll
    for (int Ti = 0; Ti < SUBNT; ++Ti) {
      const int T = g * SUBNT + Ti;
      const f16* Ab = Als + ((Ti & 1) * 2 + wr) * 8192;
      const f16* Bb = Bls + ((Ti & 1) * 2 + (wcq >> 1)) * 8192;
      // ---------------- phase 1 ----------------
      stage(T + 1, 1, 1);
      f16x8 af[8][2], bf[4][2];
#pragma unroll
      for (int m = 0; m < 8; ++m)
#pragma unroll
        for (int s = 0; s < 2; ++s)
          af[m][s] = *(const f16x8*)(Ab + abase + m * 1024 + s * 32);
#pragma unroll
      for (int n = 0; n < 4; ++n)
#pragma unroll
        for (int s = 0; s < 2; ++s)
          bf[n][s] = *(const f16x8*)(Bb + bbase + n * 1024 + s * 32);
      asm volatile("" ::: "memory");
      SBAR();
      asm volatile("s_waitcnt lgkmcnt(0)" ::: "memory");
      SFENCE();
      __builtin_amdgcn_s_setprio(1);
#pragma unroll
      for (int m = 0; m < 4; ++m)
#pragma unroll
        for (int n = 0; n < 4; ++n)
          acc[m][n] = __builtin_amdgcn_mfma_f32_16x16x32_f16(
              af[m][0], bf[n][0], acc[m][n], 0, 0, 0);
      __builtin_amdgcn_s_setprio(0);
      SBAR();
      SFENCE();
      // ---------------- phase 2 ----------------
      stage(T + 2, 0, 0);
      SBAR();
      __builtin_amdgcn_s_setprio(1);
#pragma unroll
      for (int m = 4; m < 8; ++m)
#pragma unroll
        for (int n = 0; n < 4; ++n)
          acc[m][n] = __builtin_amdgcn_mfma_f32_16x16x32_f16(
              af[m][0], bf[n][0], acc[m][n], 0, 0, 0);
      __builtin_amdgcn_s_setprio(0);
      SBAR();
      SFENCE();
      // ---------------- phase 3 ----------------
      stage(T + 2, 0, 1);
      SBAR();
      __builtin_amdgcn_s_setprio(1);
#pragma unroll
      for (int m = 0; m < 4; ++m)
#pragma unroll
        for (int n = 0; n < 4; ++n)
          acc[m][n] = __builtin_amdgcn_mfma_f32_16x16x32_f16(
              af[m][1], bf[n][1], acc[m][n], 0, 0, 0);
      __builtin_amdgcn_s_setprio(0);
      SBAR();
      SFENCE();
      // ---------------- phase 4 ----------------
      stage(T + 2, 1, 0);
      if (T + 2 < NTT) {
        asm volatile("s_waitcnt vmcnt(6)" ::: "memory");
      } else {
        asm volatile("s_waitcnt vmcnt(0)" ::: "memory");
      }
      SBAR();
      __builtin_amdgcn_s_setprio(1);
#pragma unroll
      for (int m = 4; m < 8; ++m)
#pragma unroll
        for (int n = 0; n < 4; ++n)
          acc[m][n] = __builtin_amdgcn_mfma_f32_16x16x32_f16(
              af[m][1], bf[n][1], acc[m][n], 0, 0, 0);
      __builtin_amdgcn_s_setprio(0);
      SBAR();
      SFENCE();
    }
    epi(g, acc);
#pragma unroll
    for (int zi = 0; zi < 8; ++zi)
#pragma unroll
      for (int zj = 0; zj < 4; ++zj) {
        f32x4 z = {0.f, 0.f, 0.f, 0.f};
        acc[zi][zj] = z;
      }
  }
}

// ------------------- 128x128 2-phase mainloop (for gemm_m) -----------------
__device__ __forceinline__ void run_mainloop(const f16* __restrict__ Atile,
                                             const f16* __restrict__ Btile,
                                             int lda, int ldb, int nk,
                                             f16* As, f16* Bs,
                                             f32x4 (&acc)[4][4]) {
  const int tid = threadIdx.x;
  const int lane = tid & 63;
  const int wave = tid >> 6;
  const int wr = wave >> 1, wc = wave & 1;

  auto stage = [&](int buf, int kt) {
#pragma unroll
    for (int j = 0; j < 2; ++j) {
      const int idx = j * 256 + wave * 64 + lane;
      const int row = idx >> 2;
      const int kc = idx & 3;
      GLL16(Atile + (size_t)row * lda + kt * 32 + kc * 8,
            As + buf * TILE_E + (j * 256 + wave * 64) * 8);
      GLL16(Btile + (size_t)row * ldb + kt * 32 + kc * 8,
            Bs + buf * TILE_E + (j * 256 + wave * 64) * 8);
    }
  };

  stage(0, 0);
  __syncthreads();
  for (int kt = 0; kt < nk; ++kt) {
    const int buf = kt & 1;
    if (kt + 1 < nk) stage(buf ^ 1, kt + 1);
    const f16* aB = As + buf * TILE_E;
    const f16* bB = Bs + buf * TILE_E;
    f16x8 af[4], bf[4];
#pragma unroll
    for (int i = 0; i < 4; ++i)
      af[i] = *(const f16x8*)(aB + (wr * 64 + i * 16 + (lane & 15)) * 32 +
                              ((lane >> 4) * 8));
#pragma unroll
    for (int j = 0; j < 4; ++j)
      bf[j] = *(const f16x8*)(bB + (wc * 64 + j * 16 + (lane & 15)) * 32 +
                              ((lane >> 4) * 8));
#pragma unroll
    for (int i = 0; i < 4; ++i)
#pragma unroll
      for (int j = 0; j < 4; ++j)
        acc[i][j] =
            __builtin_amdgcn_mfma_f32_16x16x32_f16(af[i], bf[j], acc[i][j],
                                                   0, 0, 0);
    __syncthreads();
  }
}

#define ZERO_ACC(acc)                                                          \
  f32x4 acc[4][4];                                                             \
  _Pragma("unroll") for (int zi = 0; zi < 4; ++zi)                             \
      _Pragma("unroll") for (int zj = 0; zj < 4; ++zj) {                       \
    f32x4 z = {0.f, 0.f, 0.f, 0.f};                                            \
    acc[zi][zj] = z;                                                           \
  }

// --------------------------- prep kernels ----------------------------------
__global__ void __launch_bounds__(256) k_cvt_x(const float* __restrict__ in,
                                               f16* __restrict__ out) {
  const int i = blockIdx.x * 256 + threadIdx.x;
  float4 v = ((const float4*)in)[i];
  f16x4 h = {(f16)v.x, (f16)v.y, (f16)v.z, (f16)v.w};
  ((f16x4*)out)[i] = h;
}

__global__ void __launch_bounds__(256) k_transpose_w(const float* __restrict__ w,
                                                     f16* __restrict__ wt,
                                                     int cols) {
  const int idx = blockIdx.x * 256 + threadIdx.x;
  const int n = idx >> 9;
  const int c = idx & 511;
  wt[idx] = (f16)w[(size_t)c * cols + n];
}

// --------------------------- GEMM kernels ----------------------------------
// qkv = relu(x @ Wqkv + b); writes q^T,k^T [C][N] f16, v [N][C] f16
// grid: 256 blocks = 2 colgroups x 16 row tiles x 8 batch; each block walks
// 3 weight column-tiles (cg*3+g) as one continuous 24-K-step pipeline.
__global__ void __launch_bounds__(512, 2)
    k_gemm_qkv(const f16* __restrict__ x16, const f16* __restrict__ wqkvt,
               const float* __restrict__ bqkv, f16* __restrict__ q_t,
               f16* __restrict__ k_t, f16* __restrict__ v16) {
  __shared__ alignas(16) f16 Als[4 * 8192];
  __shared__ alignas(16) f16 Bls[4 * 8192];
  const int l = xcd_remap(blockIdx.x, 256);
  const int cg = l & 1;
  const int by = (l >> 1) & 15;
  const int b = l >> 5;
  const char* Agb = (const char*)(x16 + ((size_t)b * N_ + by * 256) * C_);
  const char* Bgb = (const char*)(wqkvt + (size_t)cg * 3 * 256 * C_);
  const int lane = threadIdx.x & 63, wv = threadIdx.x >> 6;
  const int wr = wv >> 2, wcq = wv & 3;

  auto asrc = [&](int t) { return Agb + (t & 7) * 128; };
  auto bsrc = [&](int t) {
    return Bgb + (size_t)(t >> 3) * (256 * C_ * 2) + (t & 7) * 128;
  };
  auto epi = [&](int g, f32x4 (&acc)[8][4]) {
    const int ct = cg * 3 + g;           // column tile in [0,6)
    const int sec = ct >> 1;             // 0=q 1=k 2=v (uniform per subtile)
    const int colloc = (ct & 1) * 256 + wcq * 64;
    const int rowbase = by * 256 + wr * 128;
#pragma unroll
    for (int n = 0; n < 4; ++n) {
      const int cch = colloc + n * 16 + (lane & 15);
      const float bias = bqkv[sec * 512 + cch];
#pragma unroll
      for (int m = 0; m < 8; ++m) {
        const int n0 = rowbase + m * 16 + ((lane >> 4) << 2);
        f32x4 a = acc[m][n];
        f16x4 h = {(f16)fmaxf(a[0] + bias, 0.f), (f16)fmaxf(a[1] + bias, 0.f),
                   (f16)fmaxf(a[2] + bias, 0.f), (f16)fmaxf(a[3] + bias, 0.f)};
        if (sec == 0) {
          *(f16x4*)(q_t + ((size_t)b * C_ + cch) * N_ + n0) = h;
        } else if (sec == 1) {
          *(f16x4*)(k_t + ((size_t)b * C_ + cch) * N_ + n0) = h;
        } else {
          f16* dst = v16 + ((size_t)b * N_ + n0) * C_ + cch;
          dst[0] = h[0];
          dst[C_] = h[1];
          dst[2 * C_] = h[2];
          dst[3 * C_] = h[3];
        }
      }
    }
  };
  mainloop8p<C_ * 2, C_ * 2, 24, 8>(asrc, bsrc, Als, Bls, epi);
}

// scores partial: spart[sp][b][c][d] = sum_{n in split sp} q[n,c]k[n,d], f16
// grid: 256 blocks = 2 x 2 x (8 batch * 8 splits), NT=8 (512 n per split)
__global__ void __launch_bounds__(512, 2)
    k_gemm_scores(const f16* __restrict__ q_t, const f16* __restrict__ k_t,
                  f16* __restrict__ spart) {
  __shared__ alignas(16) f16 Als[4 * 8192];
  __shared__ alignas(16) f16 Bls[4 * 8192];
  const int l = xcd_remap(blockIdx.x, 256);
  const int bx = l & 1;
  const int by = (l >> 1) & 1;
  const int z = l >> 2;
  const int b = z >> 3, sp = z & 7;
  const char* Agb = (const char*)(q_t + (size_t)b * C_ * N_ +
                                  (size_t)(by * 256) * N_ + sp * 512);
  const char* Bgb = (const char*)(k_t + (size_t)b * C_ * N_ +
                                  (size_t)(bx * 256) * N_ + sp * 512);
  const int lane = threadIdx.x & 63, wv = threadIdx.x >> 6;
  const int wr = wv >> 2, wcq = wv & 3;

  auto asrc = [&](int t) { return Agb + t * 128; };
  auto bsrc = [&](int t) { return Bgb + t * 128; };
  f16* base = spart + (size_t)(sp * B_ + b) * C_ * C_;
  auto epi = [&](int g, f32x4 (&acc)[8][4]) {
#pragma unroll
    for (int n = 0; n < 4; ++n) {
      const int d = bx * 256 + wcq * 64 + n * 16 + (lane & 15);
#pragma unroll
      for (int m = 0; m < 8; ++m) {
        const int c0 = by * 256 + wr * 128 + m * 16 + ((lane >> 4) << 2);
#pragma unroll
        for (int r = 0; r < 4; ++r)
          base[(size_t)(c0 + r) * C_ + d] = (f16)acc[m][n][r];
      }
    }
  };
  mainloop8p<N_ * 2, N_ * 2, 8, 8>(asrc, bsrc, Als, Bls, epi);
}

// attn = softmax(sum_sp(spart)*scale, axis=-1) * adj  -> f16
__global__ void __launch_bounds__(256)
    k_softmax_gate(const f16* __restrict__ spart,
                   const float* __restrict__ adj, f16* __restrict__ attn) {
  const int b = blockIdx.x >> 9, c = blockIdx.x & 511;
  const int tid = threadIdx.x;
  const size_t ro = ((size_t)b * C_ + c) * C_;
  float s0 = 0.f, s1 = 0.f;
#pragma unroll
  for (int sp = 0; sp < 8; ++sp) {
    const f16* p = spart + (size_t)sp * B_ * C_ * C_ + ro;
    s0 += (float)p[tid];
    s1 += (float)p[tid + 256];
  }
  const float scale = 0.044194173824159216f;  // 1/sqrt(512)
  const float v0 = s0 * scale, v1 = s1 * scale;

  __shared__ float red[256];
  red[tid] = fmaxf(v0, v1);
  __syncthreads();
  for (int s = 128; s > 0; s >>= 1) {
    if (tid < s) red[tid] = fmaxf(red[tid], red[tid + s]);
    __syncthreads();
  }
  const float mx = red[0];
  __syncthreads();
  const float e0 = __expf(v0 - mx), e1 = __expf(v1 - mx);
  red[tid] = e0 + e1;
  __syncthreads();
  for (int s = 128; s > 0; s >>= 1) {
    if (tid < s) red[tid] += red[tid + s];
    __syncthreads();
  }
  const float inv = 1.0f / red[0];
  attn[ro + tid] = (f16)(e0 * inv * adj[ro + tid]);
  attn[ro + tid + 256] = (f16)(e1 * inv * adj[ro + tid + 256]);
}

// M^T[e][c] = sum_d attn[c][d] * Wo[d][e]   (small: 128^2 2-phase)
__global__ void __launch_bounds__(256)
    k_gemm_m(const f16* __restrict__ attn, const f16* __restrict__ wot,
             f16* __restrict__ mt) {
  __shared__ alignas(16) f16 As[2 * TILE_E];
  __shared__ alignas(16) f16 Bs[2 * TILE_E];
  const int b = blockIdx.z;
  const f16* Atile = attn + (size_t)b * C_ * C_ + (size_t)blockIdx.y * 128 * C_;
  const f16* Btile = wot + (size_t)blockIdx.x * 128 * C_;
  ZERO_ACC(acc);
  run_mainloop(Atile, Btile, C_, C_, C_ / 32, As, Bs, acc);

  const int tid = threadIdx.x, lane = tid & 63, wave = tid >> 6;
  const int wr = wave >> 1, wc = wave & 1;
  f16* base = mt + (size_t)b * C_ * C_;
  const int colbase = blockIdx.x * 128 + wc * 64;
  const int rowbase = blockIdx.y * 128 + wr * 64;
#pragma unroll
  for (int j = 0; j < 4; ++j) {
    const int e = colbase + j * 16 + (lane & 15);
#pragma unroll
    for (int i = 0; i < 4; ++i) {
      const int c0 = rowbase + i * 16 + ((lane >> 4) << 2);
      f32x4 a = acc[i][j];
      f16x4 h = {(f16)a[0], (f16)a[1], (f16)a[2], (f16)a[3]};
      *(f16x4*)(base + (size_t)e * C_ + c0) = h;  // transposed store
    }
  }
}

// out[n][e] = sum_c v[n][c] * M[c][e] + bo[e]   (fp32 out)
// grid: 256 blocks = 2 x 16 x 8
__global__ void __launch_bounds__(512, 2)
    k_gemm_out(const f16* __restrict__ v16, const f16* __restrict__ mt,
               const float* __restrict__ bo, float* __restrict__ out) {
  __shared__ alignas(16) f16 Als[4 * 8192];
  __shared__ alignas(16) f16 Bls[4 * 8192];
  const int l = xcd_remap(blockIdx.x, 256);
  const int bx = l & 1;
  const int by = (l >> 1) & 15;
  const int b = l >> 5;
  const char* Agb = (const char*)(v16 + ((size_t)b * N_ + by * 256) * C_);
  const char* Bgb = (const char*)(mt + (size_t)b * C_ * C_ +
                                  (size_t)(bx * 256) * C_);
  const int lane = threadIdx.x & 63, wv = threadIdx.x >> 6;
  const int wr = wv >> 2, wcq = wv & 3;

  auto asrc = [&](int t) { return Agb + t * 128; };
  auto bsrc = [&](int t) { return Bgb + t * 128; };
  float* base = out + (size_t)b * N_ * C_;
  auto epi = [&](int g, f32x4 (&acc)[8][4]) {
#pragma unroll
    for (int n = 0; n < 4; ++n) {
      const int e = bx * 256 + wcq * 64 + n * 16 + (lane & 15);
      const float bias = bo[e];
#pragma unroll
      for (int m = 0; m < 8; ++m) {
        const int n0 = by * 256 + wr * 128 + m * 16 + ((lane >> 4) << 2);
#pragma unroll
        for (int r = 0; r < 4; ++r)
          base[(size_t)(n0 + r) * C_ + e] = acc[m][n][r] + bias;
      }
    }
  };
  mainloop8p<C_ * 2, C_ * 2, 8, 8>(asrc, bsrc, Als, Bls, epi);
}

// ---------------------------------------------------------------------------
extern "C" void kernel_launch(void* const* d_in, const int* in_sizes, int n_in,
                              void* d_out, int out_size, void* d_ws,
                              size_t ws_size, hipStream_t stream) {
  const float* x = (const float*)d_in[0];
  const float* adj = (const float*)d_in[1];
  const float* Wqkv = (const float*)d_in[2];
  const float* bqkv = (const float*)d_in[3];
  const float* Wo = (const float*)d_in[4];
  const float* bo = (const float*)d_in[5];
  float* out = (float*)d_out;

  char* ws = (char*)d_ws;
  size_t off = 0;
  auto carve = [&](size_t bytes) -> char* {
    char* p = ws + off;
    off += (bytes + 255) & ~(size_t)255;
    return p;
  };
  f16* x16 = (f16*)carve((size_t)B_ * N_ * C_ * 2);       // 33.6 MB
  f16* wqkvt = (f16*)carve((size_t)3 * C_ * C_ * 2);      // 1.6 MB
  f16* wot = (f16*)carve((size_t)C_ * C_ * 2);            // 0.5 MB
  f16* q_t = (f16*)carve((size_t)B_ * C_ * N_ * 2);       // 33.6 MB
  f16* k_t = (f16*)carve((size_t)B_ * C_ * N_ * 2);       // 33.6 MB
  f16* v16 = (f16*)carve((size_t)B_ * N_ * C_ * 2);       // 33.6 MB
  // aliases over dead buffers (stream order guarantees liveness separation)
  f16* spart = x16;             // 8 splits x 8 x 512 x 512 f16 = 33.6 MB
  f16* attn16 = k_t;            // 4.2 MB, k_t dead after scores
  f16* mt16 = q_t;              // 4.2 MB, q_t dead after scores

  k_cvt_x<<<(B_ * N_ * C_ / 4) / 256, 256, 0, stream>>>(x, x16);
  k_transpose_w<<<(C_ * 3 * C_) / 256, 256, 0, stream>>>(Wqkv, wqkvt, 3 * C_);
  k_transpose_w<<<(C_ * C_) / 256, 256, 0, stream>>>(Wo, wot, C_);
  k_gemm_qkv<<<256, 512, 0, stream>>>(x16, wqkvt, bqkv, q_t, k_t, v16);
  k_gemm_scores<<<256, 512, 0, stream>>>(q_t, k_t, spart);
  k_softmax_gate<<<B_ * C_, 256, 0, stream>>>(spart, adj, attn16);
  k_gemm_m<<<dim3(4, 4, B_), 256, 0, stream>>>(attn16, wot, mt16);
  k_gemm_out<<<256, 512, 0, stream>>>(v16, mt16, bo, out);
}

// Round 4
// 179.946 us; speedup vs baseline: 1.4687x; 1.4687x over previous
//
#include <hip/hip_runtime.h>

#define B_ 8
#define N_ 4096
#define C_ 512

typedef _Float16 f16;
typedef __attribute__((ext_vector_type(8))) _Float16 f16x8;
typedef __attribute__((ext_vector_type(4))) _Float16 f16x4;
typedef __attribute__((ext_vector_type(4))) float f32x4;

#define TILE_E (128 * 32)

// global -> LDS async copy, 16B per lane. LDS dest must be wave-uniform base;
// lane adds l*16 in hardware. Global src is per-lane.
#define GLL16(gsrc, ldst)                                                      \
  __builtin_amdgcn_global_load_lds(                                            \
      (const __attribute__((address_space(1))) void*)(gsrc),                   \
      (__attribute__((address_space(3))) void*)(ldst), 16, 0, 0)

__device__ __forceinline__ int xcd_remap(int bid, int nwg) {
  // nwg % 8 == 0 for all our grids -> bijective chunked remap (T1)
  return (bid & 7) * (nwg >> 3) + (bid >> 3);
}

#define SBAR() asm volatile("s_barrier" ::: "memory")
#define SFENCE() __builtin_amdgcn_sched_barrier(0)

// ---------------------------------------------------------------------------
// 8-phase 256x256 mainloop (BK=64, 8 waves 2Mx4N, per-wave 128x64 output).
// A stored [M][LDA], B stored [N][LDB], both K-contiguous f16; K-block t of a
// tile lives at byte offset t*128 from Agb/Bgb.
// LDS: 4 half-slots/matrix of [128][64] f16 (16KB each), 128KB total.
// Swizzle (conflict-free, G4): within a half-tile, element (row,k) stored at
// physical k' = k ^ ((row&7)<<3)  (byte ^= ((row&7)<<4)). Rows 0-7 of a
// column-read hit 8 distinct 16B slots = all 32 banks; r vs r+8 is 2-way
// (free, m136). global_load_lds dest stays LINEAR; source is inverse-swizzled.
// Schedule per K-step T (4 phases):
//   ph1: stage(T+1,B1); read af x16 | bf0 x4 | bf1 x4 (sched_barrier-pinned
//        groups); bar; lgkmcnt(4); MFMA(k0,M0-3); bar
//   ph2: stage(T+2,A0); bar; MFMA(k0,M4-7); bar
//   ph3: stage(T+2,A1); bar; lgkmcnt(0); MFMA(k1,M0-3); bar
//   ph4: stage(T+2,B0); vmcnt(6|0); bar; MFMA(k1,M4-7); bar
// Slot-overwrite safety: lgkmcnt(4) at ph1 proves all 16 A-slot reads (issued
// before the 8 bf reads) retired before ph2/ph3's stage writes can land;
// lgkmcnt(0) at ph3 proves all B-slot reads retired before ph4's B0 stage.
// vmcnt(6) at ph4 leaves exactly {T+2:A0,A1,B0} outstanding -> T+1 resident.
// ---------------------------------------------------------------------------
template <int LDA2, int LDB2, int NT>
__device__ __forceinline__ void mainloop8(const char* __restrict__ Agb,
                                          const char* __restrict__ Bgb,
                                          f16* Als, f16* Bls,
                                          f32x4 (&acc)[8][4]) {
  const int tid = threadIdx.x;
  const int lane = tid & 63;
  const int wv = tid >> 6;
  const int wr = wv >> 2;   // M half (0..1)
  const int wcq = wv & 3;   // N quarter (0..3)

  // fragment read geometry (f16 elements)
  const int r15 = lane & 15;
  const int kc8 = (lane >> 4) << 3;     // k chunk base: 0,8,16,24
  const int swz = (r15 & 7) << 3;       // element-index XOR for this lane's row
  const int aoff = r15 * 64;
  const int boff = ((wcq & 1) * 64 + r15) * 64;

  // stage source offsets: LDS dest is linear; source inverse-swizzled
  int rowl[2], colb[2];
#pragma unroll
  for (int ld = 0; ld < 2; ++ld) {
    const int doff = (ld * 512 + tid) * 16;  // dest byte within half-tile
    rowl[ld] = doff >> 7;
    colb[ld] = (doff & 127) ^ ((rowl[ld] & 7) << 4);
  }

  auto stage = [&](int t, int mat, int h) {
    if (t >= NT) return;
    const char* gb = mat ? Bgb : Agb;
    const int LD2 = mat ? LDB2 : LDA2;
    f16* lsl = (mat ? Bls : Als) + ((t & 1) * 2 + h) * 8192 + wv * 512;
#pragma unroll
    for (int ld = 0; ld < 2; ++ld)
      GLL16(gb + (size_t)(h * 128 + rowl[ld]) * LD2 + (size_t)t * 128 +
                colb[ld],
            lsl + ld * 4096);
  };

  // prologue: tile0 {A0,A1,B0,B1}, tile1 {A0,A1,B0} -> 14 loads in flight
  stage(0, 0, 0); stage(0, 0, 1); stage(0, 1, 0); stage(0, 1, 1);
  stage(1, 0, 0); stage(1, 0, 1); stage(1, 1, 0);
  asm volatile("s_waitcnt vmcnt(6)" ::: "memory");  // tile0 resident
  SBAR();
  SFENCE();

  for (int T = 0; T < NT; ++T) {
    const f16* Ab = Als + ((T & 1) * 2 + wr) * 8192;
    const f16* Bb = Bls + ((T & 1) * 2 + (wcq >> 1)) * 8192;
    // ---------------- phase 1 ----------------
    stage(T + 1, 1, 1);
    f16x8 af[8][2], bf[4][2];
#pragma unroll
    for (int m = 0; m < 8; ++m)
#pragma unroll
      for (int s = 0; s < 2; ++s)
        af[m][s] =
            *(const f16x8*)(Ab + aoff + m * 1024 + ((kc8 + s * 32) ^ swz));
    SFENCE();  // pin: af group (16 reads) precedes bf groups
#pragma unroll
    for (int n = 0; n < 4; ++n)
      bf[n][0] = *(const f16x8*)(Bb + boff + n * 1024 + (kc8 ^ swz));
    SFENCE();  // pin: bf0 group (4 reads)
#pragma unroll
    for (int n = 0; n < 4; ++n)
      bf[n][1] = *(const f16x8*)(Bb + boff + n * 1024 + ((kc8 + 32) ^ swz));
    SFENCE();  // pin: bf1 group (4 reads) last
    SBAR();
    asm volatile("s_waitcnt lgkmcnt(4)" ::: "memory");  // af+bf0 done
    SFENCE();
    __builtin_amdgcn_s_setprio(1);
#pragma unroll
    for (int m = 0; m < 4; ++m)
#pragma unroll
      for (int n = 0; n < 4; ++n)
        acc[m][n] = __builtin_amdgcn_mfma_f32_16x16x32_f16(af[m][0], bf[n][0],
                                                           acc[m][n], 0, 0, 0);
    __builtin_amdgcn_s_setprio(0);
    SBAR();
    SFENCE();
    // ---------------- phase 2 ----------------
    stage(T + 2, 0, 0);
    SBAR();
    __builtin_amdgcn_s_setprio(1);
#pragma unroll
    for (int m = 4; m < 8; ++m)
#pragma unroll
      for (int n = 0; n < 4; ++n)
        acc[m][n] = __builtin_amdgcn_mfma_f32_16x16x32_f16(af[m][0], bf[n][0],
                                                           acc[m][n], 0, 0, 0);
    __builtin_amdgcn_s_setprio(0);
    SBAR();
    SFENCE();
    // ---------------- phase 3 ----------------
    stage(T + 2, 0, 1);
    SBAR();
    asm volatile("s_waitcnt lgkmcnt(0)" ::: "memory");  // bf1 done
    SFENCE();
    __builtin_amdgcn_s_setprio(1);
#pragma unroll
    for (int m = 0; m < 4; ++m)
#pragma unroll
      for (int n = 0; n < 4; ++n)
        acc[m][n] = __builtin_amdgcn_mfma_f32_16x16x32_f16(af[m][1], bf[n][1],
                                                           acc[m][n], 0, 0, 0);
    __builtin_amdgcn_s_setprio(0);
    SBAR();
    SFENCE();
    // ---------------- phase 4 ----------------
    stage(T + 2, 1, 0);
    if (T + 2 < NT) {
      asm volatile("s_waitcnt vmcnt(6)" ::: "memory");
    } else {
      asm volatile("s_waitcnt vmcnt(0)" ::: "memory");
    }
    SBAR();
    __builtin_amdgcn_s_setprio(1);
#pragma unroll
    for (int m = 4; m < 8; ++m)
#pragma unroll
      for (int n = 0; n < 4; ++n)
        acc[m][n] = __builtin_amdgcn_mfma_f32_16x16x32_f16(af[m][1], bf[n][1],
                                                           acc[m][n], 0, 0, 0);
    __builtin_amdgcn_s_setprio(0);
    SBAR();
    SFENCE();
  }
}

#define ZERO_ACC8(acc)                                                         \
  f32x4 acc[8][4];                                                             \
  _Pragma("unroll") for (int zi = 0; zi < 8; ++zi)                             \
      _Pragma("unroll") for (int zj = 0; zj < 4; ++zj) {                       \
    f32x4 z = {0.f, 0.f, 0.f, 0.f};                                            \
    acc[zi][zj] = z;                                                           \
  }

// ------------------- 128x128 2-phase mainloop (for gemm_m) -----------------
__device__ __forceinline__ void run_mainloop(const f16* __restrict__ Atile,
                                             const f16* __restrict__ Btile,
                                             int lda, int ldb, int nk,
                                             f16* As, f16* Bs,
                                             f32x4 (&acc)[4][4]) {
  const int tid = threadIdx.x;
  const int lane = tid & 63;
  const int wave = tid >> 6;
  const int wr = wave >> 1, wc = wave & 1;

  auto stage = [&](int buf, int kt) {
#pragma unroll
    for (int j = 0; j < 2; ++j) {
      const int idx = j * 256 + wave * 64 + lane;
      const int row = idx >> 2;
      const int kc = idx & 3;
      GLL16(Atile + (size_t)row * lda + kt * 32 + kc * 8,
            As + buf * TILE_E + (j * 256 + wave * 64) * 8);
      GLL16(Btile + (size_t)row * ldb + kt * 32 + kc * 8,
            Bs + buf * TILE_E + (j * 256 + wave * 64) * 8);
    }
  };

  stage(0, 0);
  __syncthreads();
  for (int kt = 0; kt < nk; ++kt) {
    const int buf = kt & 1;
    if (kt + 1 < nk) stage(buf ^ 1, kt + 1);
    const f16* aB = As + buf * TILE_E;
    const f16* bB = Bs + buf * TILE_E;
    f16x8 af[4], bf[4];
#pragma unroll
    for (int i = 0; i < 4; ++i)
      af[i] = *(const f16x8*)(aB + (wr * 64 + i * 16 + (lane & 15)) * 32 +
                              ((lane >> 4) * 8));
#pragma unroll
    for (int j = 0; j < 4; ++j)
      bf[j] = *(const f16x8*)(bB + (wc * 64 + j * 16 + (lane & 15)) * 32 +
                              ((lane >> 4) * 8));
#pragma unroll
    for (int i = 0; i < 4; ++i)
#pragma unroll
      for (int j = 0; j < 4; ++j)
        acc[i][j] =
            __builtin_amdgcn_mfma_f32_16x16x32_f16(af[i], bf[j], acc[i][j],
                                                   0, 0, 0);
    __syncthreads();
  }
}

#define ZERO_ACC(acc)                                                          \
  f32x4 acc[4][4];                                                             \
  _Pragma("unroll") for (int zi = 0; zi < 4; ++zi)                             \
      _Pragma("unroll") for (int zj = 0; zj < 4; ++zj) {                       \
    f32x4 z = {0.f, 0.f, 0.f, 0.f};                                            \
    acc[zi][zj] = z;                                                           \
  }

// --------------------------- prep kernels ----------------------------------
__global__ void __launch_bounds__(256) k_cvt_x(const float* __restrict__ in,
                                               f16* __restrict__ out) {
  const int i = blockIdx.x * 256 + threadIdx.x;
  float4 v = ((const float4*)in)[i];
  f16x4 h = {(f16)v.x, (f16)v.y, (f16)v.z, (f16)v.w};
  ((f16x4*)out)[i] = h;
}

__global__ void __launch_bounds__(256) k_transpose_w(const float* __restrict__ w,
                                                     f16* __restrict__ wt,
                                                     int cols) {
  const int idx = blockIdx.x * 256 + threadIdx.x;
  const int n = idx >> 9;
  const int c = idx & 511;
  wt[idx] = (f16)w[(size_t)c * cols + n];
}

// --------------------------- GEMM kernels ----------------------------------
// qkv = relu(x @ Wqkv + b); writes q^T,k^T [C][N] f16, v [N][C] f16
// grid: 768 blocks = 6 (col tiles) x 16 (row tiles) x 8 (batch)
__global__ void __launch_bounds__(512, 2)
    k_gemm_qkv(const f16* __restrict__ x16, const f16* __restrict__ wqkvt,
               const float* __restrict__ bqkv, f16* __restrict__ q_t,
               f16* __restrict__ k_t, f16* __restrict__ v16) {
  __shared__ alignas(16) f16 Als[4 * 8192];
  __shared__ alignas(16) f16 Bls[4 * 8192];
  const int l = xcd_remap(blockIdx.x, 768);
  const int bx = l % 6;          // consecutive l -> same x panel (L2 reuse)
  const int rest = l / 6;
  const int by = rest & 15;
  const int b = rest >> 4;
  const char* Agb = (const char*)(x16 + ((size_t)b * N_ + by * 256) * C_);
  const char* Bgb = (const char*)(wqkvt + (size_t)bx * 256 * C_);
  ZERO_ACC8(acc);
  mainloop8<C_ * 2, C_ * 2, C_ / 64>(Agb, Bgb, Als, Bls, acc);

  const int lane = threadIdx.x & 63, wv = threadIdx.x >> 6;
  const int wr = wv >> 2, wcq = wv & 3;
  const int sec = bx >> 1;  // 0=q 1=k 2=v, uniform per block
  const int colloc = (bx & 1) * 256 + wcq * 64;
  const int rowbase = by * 256 + wr * 128;
#pragma unroll
  for (int n = 0; n < 4; ++n) {
    const int cch = colloc + n * 16 + (lane & 15);
    const float bias = bqkv[sec * 512 + cch];
#pragma unroll
    for (int m = 0; m < 8; ++m) {
      const int n0 = rowbase + m * 16 + ((lane >> 4) << 2);
      f32x4 a = acc[m][n];
      f16x4 h = {(f16)fmaxf(a[0] + bias, 0.f), (f16)fmaxf(a[1] + bias, 0.f),
                 (f16)fmaxf(a[2] + bias, 0.f), (f16)fmaxf(a[3] + bias, 0.f)};
      if (sec == 0) {
        *(f16x4*)(q_t + ((size_t)b * C_ + cch) * N_ + n0) = h;
      } else if (sec == 1) {
        *(f16x4*)(k_t + ((size_t)b * C_ + cch) * N_ + n0) = h;
      } else {
        f16* dst = v16 + ((size_t)b * N_ + n0) * C_ + cch;
        dst[0] = h[0];
        dst[C_] = h[1];
        dst[2 * C_] = h[2];
        dst[3 * C_] = h[3];
      }
    }
  }
}

// scores partial: spart[sp][b][c][d] = sum_{n in split sp} q[n,c]k[n,d], f16
// grid: 256 blocks = 2 x 2 x (8 batch * 8 splits), NT=8 (512 n per split)
__global__ void __launch_bounds__(512, 2)
    k_gemm_scores(const f16* __restrict__ q_t, const f16* __restrict__ k_t,
                  f16* __restrict__ spart) {
  __shared__ alignas(16) f16 Als[4 * 8192];
  __shared__ alignas(16) f16 Bls[4 * 8192];
  const int l = xcd_remap(blockIdx.x, 256);
  const int bx = l & 1;
  const int by = (l >> 1) & 1;
  const int z = l >> 2;
  const int b = z >> 3, sp = z & 7;
  const char* Agb = (const char*)(q_t + (size_t)b * C_ * N_ +
                                  (size_t)(by * 256) * N_ + sp * 512);
  const char* Bgb = (const char*)(k_t + (size_t)b * C_ * N_ +
                                  (size_t)(bx * 256) * N_ + sp * 512);
  ZERO_ACC8(acc);
  mainloop8<N_ * 2, N_ * 2, 8>(Agb, Bgb, Als, Bls, acc);

  const int lane = threadIdx.x & 63, wv = threadIdx.x >> 6;
  const int wr = wv >> 2, wcq = wv & 3;
  f16* base = spart + (size_t)(sp * B_ + b) * C_ * C_;
#pragma unroll
  for (int n = 0; n < 4; ++n) {
    const int d = bx * 256 + wcq * 64 + n * 16 + (lane & 15);
#pragma unroll
    for (int m = 0; m < 8; ++m) {
      const int c0 = by * 256 + wr * 128 + m * 16 + ((lane >> 4) << 2);
#pragma unroll
      for (int r = 0; r < 4; ++r)
        base[(size_t)(c0 + r) * C_ + d] = (f16)acc[m][n][r];
    }
  }
}

// attn = softmax(sum_sp(spart)*scale, axis=-1) * adj  -> f16
__global__ void __launch_bounds__(256)
    k_softmax_gate(const f16* __restrict__ spart,
                   const float* __restrict__ adj, f16* __restrict__ attn) {
  const int b = blockIdx.x >> 9, c = blockIdx.x & 511;
  const int tid = threadIdx.x;
  const size_t ro = ((size_t)b * C_ + c) * C_;
  float s0 = 0.f, s1 = 0.f;
#pragma unroll
  for (int sp = 0; sp < 8; ++sp) {
    const f16* p = spart + (size_t)sp * B_ * C_ * C_ + ro;
    s0 += (float)p[tid];
    s1 += (float)p[tid + 256];
  }
  const float scale = 0.044194173824159216f;  // 1/sqrt(512)
  const float v0 = s0 * scale, v1 = s1 * scale;

  __shared__ float red[256];
  red[tid] = fmaxf(v0, v1);
  __syncthreads();
  for (int s = 128; s > 0; s >>= 1) {
    if (tid < s) red[tid] = fmaxf(red[tid], red[tid + s]);
    __syncthreads();
  }
  const float mx = red[0];
  __syncthreads();
  const float e0 = __expf(v0 - mx), e1 = __expf(v1 - mx);
  red[tid] = e0 + e1;
  __syncthreads();
  for (int s = 128; s > 0; s >>= 1) {
    if (tid < s) red[tid] += red[tid + s];
    __syncthreads();
  }
  const float inv = 1.0f / red[0];
  attn[ro + tid] = (f16)(e0 * inv * adj[ro + tid]);
  attn[ro + tid + 256] = (f16)(e1 * inv * adj[ro + tid + 256]);
}

// M^T[e][c] = sum_d attn[c][d] * Wo[d][e]   (small: 128^2 2-phase)
__global__ void __launch_bounds__(256)
    k_gemm_m(const f16* __restrict__ attn, const f16* __restrict__ wot,
             f16* __restrict__ mt) {
  __shared__ alignas(16) f16 As[2 * TILE_E];
  __shared__ alignas(16) f16 Bs[2 * TILE_E];
  const int b = blockIdx.z;
  const f16* Atile = attn + (size_t)b * C_ * C_ + (size_t)blockIdx.y * 128 * C_;
  const f16* Btile = wot + (size_t)blockIdx.x * 128 * C_;
  ZERO_ACC(acc);
  run_mainloop(Atile, Btile, C_, C_, C_ / 32, As, Bs, acc);

  const int tid = threadIdx.x, lane = tid & 63, wave = tid >> 6;
  const int wr = wave >> 1, wc = wave & 1;
  f16* base = mt + (size_t)b * C_ * C_;
  const int colbase = blockIdx.x * 128 + wc * 64;
  const int rowbase = blockIdx.y * 128 + wr * 64;
#pragma unroll
  for (int j = 0; j < 4; ++j) {
    const int e = colbase + j * 16 + (lane & 15);
#pragma unroll
    for (int i = 0; i < 4; ++i) {
      const int c0 = rowbase + i * 16 + ((lane >> 4) << 2);
      f32x4 a = acc[i][j];
      f16x4 h = {(f16)a[0], (f16)a[1], (f16)a[2], (f16)a[3]};
      *(f16x4*)(base + (size_t)e * C_ + c0) = h;  // transposed store
    }
  }
}

// out[n][e] = sum_c v[n][c] * M[c][e] + bo[e]   (fp32 out)
// grid: 256 blocks = 2 x 16 x 8
__global__ void __launch_bounds__(512, 2)
    k_gemm_out(const f16* __restrict__ v16, const f16* __restrict__ mt,
               const float* __restrict__ bo, float* __restrict__ out) {
  __shared__ alignas(16) f16 Als[4 * 8192];
  __shared__ alignas(16) f16 Bls[4 * 8192];
  const int l = xcd_remap(blockIdx.x, 256);
  const int bx = l & 1;
  const int by = (l >> 1) & 15;
  const int b = l >> 5;
  const char* Agb = (const char*)(v16 + ((size_t)b * N_ + by * 256) * C_);
  const char* Bgb = (const char*)(mt + (size_t)b * C_ * C_ +
                                  (size_t)(bx * 256) * C_);
  ZERO_ACC8(acc);
  mainloop8<C_ * 2, C_ * 2, 8>(Agb, Bgb, Als, Bls, acc);

  const int lane = threadIdx.x & 63, wv = threadIdx.x >> 6;
  const int wr = wv >> 2, wcq = wv & 3;
  float* base = out + (size_t)b * N_ * C_;
#pragma unroll
  for (int n = 0; n < 4; ++n) {
    const int e = bx * 256 + wcq * 64 + n * 16 + (lane & 15);
    const float bias = bo[e];
#pragma unroll
    for (int m = 0; m < 8; ++m) {
      const int n0 = by * 256 + wr * 128 + m * 16 + ((lane >> 4) << 2);
#pragma unroll
      for (int r = 0; r < 4; ++r)
        base[(size_t)(n0 + r) * C_ + e] = acc[m][n][r] + bias;
    }
  }
}

// ---------------------------------------------------------------------------
extern "C" void kernel_launch(void* const* d_in, const int* in_sizes, int n_in,
                              void* d_out, int out_size, void* d_ws,
                              size_t ws_size, hipStream_t stream) {
  const float* x = (const float*)d_in[0];
  const float* adj = (const float*)d_in[1];
  const float* Wqkv = (const float*)d_in[2];
  const float* bqkv = (const float*)d_in[3];
  const float* Wo = (const float*)d_in[4];
  const float* bo = (const float*)d_in[5];
  float* out = (float*)d_out;

  char* ws = (char*)d_ws;
  size_t off = 0;
  auto carve = [&](size_t bytes) -> char* {
    char* p = ws + off;
    off += (bytes + 255) & ~(size_t)255;
    return p;
  };
  f16* x16 = (f16*)carve((size_t)B_ * N_ * C_ * 2);       // 33.6 MB
  f16* wqkvt = (f16*)carve((size_t)3 * C_ * C_ * 2);      // 1.6 MB
  f16* wot = (f16*)carve((size_t)C_ * C_ * 2);            // 0.5 MB
  f16* q_t = (f16*)carve((size_t)B_ * C_ * N_ * 2);       // 33.6 MB
  f16* k_t = (f16*)carve((size_t)B_ * C_ * N_ * 2);       // 33.6 MB
  f16* v16 = (f16*)carve((size_t)B_ * N_ * C_ * 2);       // 33.6 MB
  // aliases over dead buffers (stream order guarantees liveness separation)
  f16* spart = x16;             // 8 splits x 8 x 512 x 512 f16 = 33.6 MB
  f16* attn16 = k_t;            // 4.2 MB, k_t dead after scores
  f16* mt16 = q_t;              // 4.2 MB, q_t dead after scores

  k_cvt_x<<<(B_ * N_ * C_ / 4) / 256, 256, 0, stream>>>(x, x16);
  k_transpose_w<<<(C_ * 3 * C_) / 256, 256, 0, stream>>>(Wqkv, wqkvt, 3 * C_);
  k_transpose_w<<<(C_ * C_) / 256, 256, 0, stream>>>(Wo, wot, C_);
  k_gemm_qkv<<<768, 512, 0, stream>>>(x16, wqkvt, bqkv, q_t, k_t, v16);
  k_gemm_scores<<<256, 512, 0, stream>>>(q_t, k_t, spart);
  k_softmax_gate<<<B_ * C_, 256, 0, stream>>>(spart, adj, attn16);
  k_gemm_m<<<dim3(4, 4, B_), 256, 0, stream>>>(attn16, wot, mt16);
  k_gemm_out<<<256, 512, 0, stream>>>(v16, mt16, bo, out);
}